// Round 3
// baseline (798.841 us; speedup 1.0000x reference)
//
#include <hip/hip_runtime.h>

#define N_ROWS 65536
#define DIM 512       // NDIM == K == 512
#define MKNOTS 200
#define KT 16         // spline k-cols per block
#define NCHUNK 4096   // spline n-rows per block (8 iters x 512 threads)
#define NCELL 768     // bucket cells over [-4, 8], cell = 1/64 < min knot gap 0.0201

typedef _Float16 f16x8 __attribute__((ext_vector_type(8)));
typedef _Float16 f16x4 __attribute__((ext_vector_type(4)));
typedef float f32x4 __attribute__((ext_vector_type(4)));

__device__ inline void gload16(const void* g, void* l) {
  __builtin_amdgcn_global_load_lds(
      (const __attribute__((address_space(1))) void*)g,
      (__attribute__((address_space(3))) void*)l,
      16, 0, 0);
}

// ---------------------------------------------------------------------------
// GEMM (unchanged from round 1 — passing): C = A * Bt^T (+ addsrc), f16 MFMA,
// S3 = hi/lo split-3 for fp32-quality accumulation.
// ---------------------------------------------------------------------------
template <bool S3, bool ADDSRC>
__global__ __launch_bounds__(256)
void gemm_k(const _Float16* __restrict__ Ah, const _Float16* __restrict__ Al,
            const _Float16* __restrict__ Bth, const _Float16* __restrict__ Btl,
            const float* __restrict__ addsrc, float* __restrict__ C)
{
  __shared__ alignas(16) _Float16 smem[S3 ? 16384 : 8192];
  _Float16* sAh = smem;            // 128*32
  _Float16* sBh = smem + 4096;     // 128*32 (Bt rows = n)
  _Float16* sAl = S3 ? smem + 8192  : smem;
  _Float16* sBl = S3 ? smem + 12288 : smem;

  const int tid  = threadIdx.x;
  const int bm   = blockIdx.x * 128;
  const int bn   = blockIdx.y * 128;
  const int wm   = ((tid >> 6) >> 1) * 64;
  const int wn   = ((tid >> 6) & 1) * 64;
  const int lane = tid & 63;
  const int lm   = lane & 15;
  const int quad = lane >> 4;
  const int sr   = tid >> 2;        // staging row 0..63
  const int sc   = (tid & 3) * 8;   // staging col chunk (8 f16 = 16B)

  const _Float16* gAh = Ah  + (size_t)(bm + sr) * DIM + sc;
  const _Float16* gBh = Bth + (size_t)(bn + sr) * DIM + sc;
  const _Float16* gAl = S3 ? (Al  + (size_t)(bm + sr) * DIM + sc) : gAh;
  const _Float16* gBl = S3 ? (Btl + (size_t)(bn + sr) * DIM + sc) : gBh;

  f32x4 acc[4][4] = {};

  for (int k0 = 0; k0 < DIM; k0 += 32) {
    gload16(gAh + k0,               sAh + tid * 8);
    gload16(gAh + k0 + 64 * DIM,    sAh + 2048 + tid * 8);
    gload16(gBh + k0,               sBh + tid * 8);
    gload16(gBh + k0 + 64 * DIM,    sBh + 2048 + tid * 8);
    if constexpr (S3) {
      gload16(gAl + k0,             sAl + tid * 8);
      gload16(gAl + k0 + 64 * DIM,  sAl + 2048 + tid * 8);
      gload16(gBl + k0,             sBl + tid * 8);
      gload16(gBl + k0 + 64 * DIM,  sBl + 2048 + tid * 8);
    }
    __syncthreads();

    f16x8 a_h[4], b_h[4], a_l[4], b_l[4];
    #pragma unroll
    for (int i = 0; i < 4; ++i) {
      a_h[i] = *(const f16x8*)&sAh[(wm + i * 16 + lm) * 32 + quad * 8];
      b_h[i] = *(const f16x8*)&sBh[(wn + i * 16 + lm) * 32 + quad * 8];
      if constexpr (S3) {
        a_l[i] = *(const f16x8*)&sAl[(wm + i * 16 + lm) * 32 + quad * 8];
        b_l[i] = *(const f16x8*)&sBl[(wn + i * 16 + lm) * 32 + quad * 8];
      }
    }
    #pragma unroll
    for (int i = 0; i < 4; ++i)
      #pragma unroll
      for (int j = 0; j < 4; ++j) {
        acc[i][j] = __builtin_amdgcn_mfma_f32_16x16x32_f16(a_h[i], b_h[j], acc[i][j], 0, 0, 0);
        if constexpr (S3) {
          acc[i][j] = __builtin_amdgcn_mfma_f32_16x16x32_f16(a_h[i], b_l[j], acc[i][j], 0, 0, 0);
          acc[i][j] = __builtin_amdgcn_mfma_f32_16x16x32_f16(a_l[i], b_h[j], acc[i][j], 0, 0, 0);
        }
      }
    __syncthreads();
  }

  // C/D layout (verified m89/m91): col = lane&15, row = quad*4 + reg
  #pragma unroll
  for (int i = 0; i < 4; ++i)
    #pragma unroll
    for (int j = 0; j < 4; ++j)
      #pragma unroll
      for (int r = 0; r < 4; ++r) {
        const int row = bm + wm + i * 16 + quad * 4 + r;
        const int col = bn + wn + j * 16 + lm;
        const size_t idx = (size_t)row * DIM + col;
        float v = acc[i][j][r];
        if constexpr (ADDSRC) v += addsrc[idx];
        C[idx] = v;
      }
}

// ---------------------------------------------------------------------------
// fp32 -> f16 hi/lo split of data
// ---------------------------------------------------------------------------
__global__ __launch_bounds__(256)
void conv_data_k(const float* __restrict__ in, _Float16* __restrict__ hi,
                 _Float16* __restrict__ lo)
{
  const size_t i = ((size_t)blockIdx.x * 256 + threadIdx.x) * 4;
  const float4 v = *reinterpret_cast<const float4*>(in + i);
  f16x4 h, l;
  h.x = (_Float16)v.x; l.x = (_Float16)(v.x - (float)h.x);
  h.y = (_Float16)v.y; l.y = (_Float16)(v.y - (float)h.y);
  h.z = (_Float16)v.z; l.z = (_Float16)(v.z - (float)h.z);
  h.w = (_Float16)v.w; l.w = (_Float16)(v.w - (float)h.w);
  *reinterpret_cast<f16x4*>(hi + i) = h;
  *reinterpret_cast<f16x4*>(lo + i) = l;
}

__global__ __launch_bounds__(256)
void conv_A_k(const float* __restrict__ A, _Float16* __restrict__ Ah,
              _Float16* __restrict__ Al, _Float16* __restrict__ ATh,
              _Float16* __restrict__ ATl)
{
  const int i = blockIdx.x * 256 + threadIdx.x;
  const int r = i >> 9, c = i & 511;
  const float v = A[i];
  const _Float16 h = (_Float16)v;
  const _Float16 l = (_Float16)(v - (float)h);
  Ah[i] = h; Al[i] = l;
  ATh[c * 512 + r] = h; ATl[c * 512 + r] = l;
}

// ---------------------------------------------------------------------------
// Spline prep (unchanged): pkG[k][j] = {x,y,d,s}; bucketG[k][c] = #{x_j <= cell_left}
// ---------------------------------------------------------------------------
__global__ __launch_bounds__(256)
void prep_k(const float* __restrict__ xx, const float* __restrict__ yy,
            const float* __restrict__ dd, float4* __restrict__ pkG,
            unsigned char* __restrict__ bucketG)
{
  __shared__ float xr[MKNOTS], yr[MKNOTS];
  const int k = blockIdx.x, tid = threadIdx.x;
  if (tid < MKNOTS) {
    xr[tid] = xx[k * MKNOTS + tid];
    yr[tid] = yy[k * MKNOTS + tid];
  }
  __syncthreads();
  if (tid < MKNOTS) {
    const float x0 = xr[tid], y0 = yr[tid], d0 = dd[k * MKNOTS + tid];
    float s = 0.f;
    if (tid < MKNOTS - 1) s = (yr[tid + 1] - y0) / (xr[tid + 1] - x0);
    pkG[k * MKNOTS + tid] = float4{x0, y0, d0, s};
  }
  for (int c = tid; c < NCELL; c += 256) {
    const float cl = -4.f + (float)c * 0.015625f;
    int lo = 0, hi = MKNOTS;
    while (lo < hi) { const int mid = (lo + hi) >> 1; if (xr[mid] <= cl) lo = mid + 1; else hi = mid; }
    bucketG[k * NCELL + c] = (unsigned char)lo;
  }
}

// ---------------------------------------------------------------------------
// RQ spline v3: thread-per-row. Each thread owns data0[n][kBase..kBase+15]
// (exactly one 64B cache line, 4 x dwordx4), does 16 independent evals (ILP),
// accumulates logd in a REGISTER (no shuffles), writes 32B contiguous zH,
// one atomic per 16 elements. LDS chain per eval: u8 cnt -> b128 P -> b128 Q.
// ---------------------------------------------------------------------------
__global__ __launch_bounds__(512, 4)
void spline_k(const float* __restrict__ data0, const float4* __restrict__ pkG,
              const unsigned char* __restrict__ bucketG,
              _Float16* __restrict__ zH, float* __restrict__ logj)
{
  __shared__ float4 sPK[KT * (MKNOTS + 1)];   // row stride 201 float4s
  __shared__ unsigned int sBkt32[KT * 193];   // row stride 193 words (772 B)

  const int kBase = blockIdx.x * KT;
  const int nBase = blockIdx.y * NCHUNK;
  const int tid = threadIdx.x;

  for (int i = tid; i < KT * MKNOTS; i += 512) {
    const int r = i / MKNOTS, c = i - r * MKNOTS;
    sPK[r * (MKNOTS + 1) + c] = pkG[(kBase + r) * MKNOTS + c];
  }
  const unsigned int* bG32 = (const unsigned int*)bucketG;
  for (int i = tid; i < KT * (NCELL / 4); i += 512) {
    const int r = i / (NCELL / 4), c = i - r * (NCELL / 4);
    sBkt32[r * 193 + c] = bG32[(kBase + r) * (NCELL / 4) + c];
  }
  __syncthreads();

  float4 cur[4], nxt[4];
  {
    const float4* p4 = (const float4*)(data0 + (size_t)(nBase + tid) * DIM + kBase);
    #pragma unroll
    for (int q = 0; q < 4; ++q) cur[q] = p4[q];
  }

  for (int it = 0; it < NCHUNK / 512; ++it) {
    const int n = nBase + it * 512 + tid;
    if (it + 1 < NCHUNK / 512) {
      const float4* p4 = (const float4*)(data0 + (size_t)(n + 512) * DIM + kBase);
      #pragma unroll
      for (int q = 0; q < 4; ++q) nxt[q] = p4[q];
    }

    float acc = 0.f;
    f16x8 z0, z1;
    #pragma unroll
    for (int j = 0; j < 16; ++j) {
      const float x = ((const float*)cur)[j];
      const float4* prow = sPK + j * (MKNOTS + 1);
      const unsigned char* brow = (const unsigned char*)sBkt32 + j * 772;

      int cnt0 = 0;
      if (x > -4.f) {
        int c = (int)((x + 4.f) * 64.f);
        c = min(c, NCELL - 1);
        cnt0 = (int)brow[c];
      }
      const int p = min(cnt0, MKNOTS - 1);
      const float4 P = prow[p];
      const bool take = (cnt0 <= MKNOTS - 1) && (P.x < x);
      const int idx = cnt0 + (take ? 1 : 0);
      const int qi = min(max(take ? p + 1 : p - 1, 0), MKNOTS - 1);
      const float4 Q = prow[qi];
      const bool edge = (idx == 0) || (idx >= MKNOTS);
      // interior interval: take -> [P, Q], else [Q, P]
      const float4 pa = take ? P : Q;
      const float4 pb = take ? Q : P;

      const float dxk = pb.x - pa.x;
      float xi = (x - pa.x) * __builtin_amdgcn_rcpf(dxk);
      xi = fminf(fmaxf(xi, 0.f), 1.f);
      const float xi1 = 1.f - xi;
      const float t = pa.w;                  // s = dy/dx (precomputed)
      const float g = xi * xi1;
      const float den = t + (pb.z + pa.z - 2.f * t) * g;
      const float rden = __builtin_amdgcn_rcpf(den);
      float y = pa.y + t * dxk * (t * xi * xi + pa.z * g) * rden;
      const float dnum = pb.z * xi * xi + 2.f * t * g + pa.z * xi1 * xi1;
      float logd = __logf(t * t * dnum * rden * rden);
      if (edge) {                            // below uses P=knot0, above uses P=knot199
        y = P.y + P.z * (x - P.x);
        logd = __logf(P.z);
      }
      acc += logd;
      const _Float16 zz = (_Float16)(y - x);
      if (j < 8) z0[j] = zz; else z1[j - 8] = zz;
    }

    _Float16* zp = zH + (size_t)n * DIM + kBase;
    *(f16x8*)zp = z0;
    *((f16x8*)zp + 1) = z1;
    atomicAdd(&logj[n], acc);

    #pragma unroll
    for (int q = 0; q < 4; ++q) cur[q] = nxt[q];
  }
}

// ---------------------------------------------------------------------------
extern "C" void kernel_launch(void* const* d_in, const int* in_sizes, int n_in,
                              void* d_out, int out_size, void* d_ws, size_t ws_size,
                              hipStream_t stream)
{
  const float* data  = (const float*)d_in[0];
  const float* A     = (const float*)d_in[1];
  const float* xx    = (const float*)d_in[2];
  const float* yy    = (const float*)d_in[3];
  const float* delta = (const float*)d_in[4];

  float* out  = (float*)d_out;                       // N_ROWS * DIM
  float* logj = out + (size_t)N_ROWS * DIM;          // N_ROWS

  // workspace layout (~258 MiB)
  _Float16* dHi = (_Float16*)d_ws;                   // 64 MiB
  _Float16* dLo = dHi + (size_t)N_ROWS * DIM;        // 64 MiB
  _Float16* Ah  = dLo + (size_t)N_ROWS * DIM;        // 512 KiB each
  _Float16* Al  = Ah + 512 * 512;
  _Float16* ATh = Al + 512 * 512;
  _Float16* ATl = ATh + 512 * 512;
  float* data0  = (float*)(ATl + 512 * 512);         // 128 MiB
  _Float16* zH  = dHi;                               // alias: dHi dead after GEMM1
  float4* pkG = (float4*)dLo;                        // alias: dLo dead after GEMM1
  unsigned char* bucketG = (unsigned char*)(pkG + 512 * MKNOTS);

  conv_A_k<<<1024, 256, 0, stream>>>(A, Ah, Al, ATh, ATl);
  conv_data_k<<<(N_ROWS * DIM) / (256 * 4), 256, 0, stream>>>(data, dHi, dLo);

  // data0 = data @ A  (split-3 f16, fp32-quality)
  gemm_k<true, false><<<dim3(N_ROWS / 128, DIM / 128), 256, 0, stream>>>(
      dHi, dLo, ATh, ATl, nullptr, data0);

  prep_k<<<512, 256, 0, stream>>>(xx, yy, delta, pkG, bucketG);
  hipMemsetAsync(logj, 0, N_ROWS * sizeof(float), stream);

  spline_k<<<dim3(DIM / KT, N_ROWS / NCHUNK), 512, 0, stream>>>(
      data0, pkG, bucketG, zH, logj);

  // out = data + z @ A^T  (plain f16)
  gemm_k<false, true><<<dim3(N_ROWS / 128, DIM / 128), 256, 0, stream>>>(
      zH, nullptr, Ah, nullptr, data, out);
}

// Round 4
// 607.263 us; speedup vs baseline: 1.3155x; 1.3155x over previous
//
#include <hip/hip_runtime.h>

#define N_ROWS 65536
#define DIM 512       // NDIM == K == 512
#define MKNOTS 200
#define KT 16         // spline k-cols per block
#define NCELL 384     // bucket cells over [-4,8], cell = 1/32; knot gap >= 0.0201 -> <=2 knots/cell
#define TILE 256      // spline rows per tile (= threads)
#define TPB 4         // tiles per block

typedef _Float16 f16x8 __attribute__((ext_vector_type(8)));
typedef _Float16 f16x4 __attribute__((ext_vector_type(4)));
typedef float f32x4 __attribute__((ext_vector_type(4)));

__device__ inline void gload16(const void* g, void* l) {
  __builtin_amdgcn_global_load_lds(
      (const __attribute__((address_space(1))) void*)g,
      (__attribute__((address_space(3))) void*)l,
      16, 0, 0);
}

// ---------------------------------------------------------------------------
// GEMM (unchanged from round 1 — passing): C = A * Bt^T (+ addsrc), f16 MFMA,
// S3 = hi/lo split-3 for fp32-quality accumulation.
// ---------------------------------------------------------------------------
template <bool S3, bool ADDSRC>
__global__ __launch_bounds__(256)
void gemm_k(const _Float16* __restrict__ Ah, const _Float16* __restrict__ Al,
            const _Float16* __restrict__ Bth, const _Float16* __restrict__ Btl,
            const float* __restrict__ addsrc, float* __restrict__ C)
{
  __shared__ alignas(16) _Float16 smem[S3 ? 16384 : 8192];
  _Float16* sAh = smem;            // 128*32
  _Float16* sBh = smem + 4096;     // 128*32 (Bt rows = n)
  _Float16* sAl = S3 ? smem + 8192  : smem;
  _Float16* sBl = S3 ? smem + 12288 : smem;

  const int tid  = threadIdx.x;
  const int bm   = blockIdx.x * 128;
  const int bn   = blockIdx.y * 128;
  const int wm   = ((tid >> 6) >> 1) * 64;
  const int wn   = ((tid >> 6) & 1) * 64;
  const int lane = tid & 63;
  const int lm   = lane & 15;
  const int quad = lane >> 4;
  const int sr   = tid >> 2;        // staging row 0..63
  const int sc   = (tid & 3) * 8;   // staging col chunk (8 f16 = 16B)

  const _Float16* gAh = Ah  + (size_t)(bm + sr) * DIM + sc;
  const _Float16* gBh = Bth + (size_t)(bn + sr) * DIM + sc;
  const _Float16* gAl = S3 ? (Al  + (size_t)(bm + sr) * DIM + sc) : gAh;
  const _Float16* gBl = S3 ? (Btl + (size_t)(bn + sr) * DIM + sc) : gBh;

  f32x4 acc[4][4] = {};

  for (int k0 = 0; k0 < DIM; k0 += 32) {
    gload16(gAh + k0,               sAh + tid * 8);
    gload16(gAh + k0 + 64 * DIM,    sAh + 2048 + tid * 8);
    gload16(gBh + k0,               sBh + tid * 8);
    gload16(gBh + k0 + 64 * DIM,    sBh + 2048 + tid * 8);
    if constexpr (S3) {
      gload16(gAl + k0,             sAl + tid * 8);
      gload16(gAl + k0 + 64 * DIM,  sAl + 2048 + tid * 8);
      gload16(gBl + k0,             sBl + tid * 8);
      gload16(gBl + k0 + 64 * DIM,  sBl + 2048 + tid * 8);
    }
    __syncthreads();

    f16x8 a_h[4], b_h[4], a_l[4], b_l[4];
    #pragma unroll
    for (int i = 0; i < 4; ++i) {
      a_h[i] = *(const f16x8*)&sAh[(wm + i * 16 + lm) * 32 + quad * 8];
      b_h[i] = *(const f16x8*)&sBh[(wn + i * 16 + lm) * 32 + quad * 8];
      if constexpr (S3) {
        a_l[i] = *(const f16x8*)&sAl[(wm + i * 16 + lm) * 32 + quad * 8];
        b_l[i] = *(const f16x8*)&sBl[(wn + i * 16 + lm) * 32 + quad * 8];
      }
    }
    #pragma unroll
    for (int i = 0; i < 4; ++i)
      #pragma unroll
      for (int j = 0; j < 4; ++j) {
        acc[i][j] = __builtin_amdgcn_mfma_f32_16x16x32_f16(a_h[i], b_h[j], acc[i][j], 0, 0, 0);
        if constexpr (S3) {
          acc[i][j] = __builtin_amdgcn_mfma_f32_16x16x32_f16(a_h[i], b_l[j], acc[i][j], 0, 0, 0);
          acc[i][j] = __builtin_amdgcn_mfma_f32_16x16x32_f16(a_l[i], b_h[j], acc[i][j], 0, 0, 0);
        }
      }
    __syncthreads();
  }

  // C/D layout (verified m89/m91): col = lane&15, row = quad*4 + reg
  #pragma unroll
  for (int i = 0; i < 4; ++i)
    #pragma unroll
    for (int j = 0; j < 4; ++j)
      #pragma unroll
      for (int r = 0; r < 4; ++r) {
        const int row = bm + wm + i * 16 + quad * 4 + r;
        const int col = bn + wn + j * 16 + lm;
        const size_t idx = (size_t)row * DIM + col;
        float v = acc[i][j][r];
        if constexpr (ADDSRC) v += addsrc[idx];
        C[idx] = v;
      }
}

// ---------------------------------------------------------------------------
// fp32 -> f16 hi/lo split of data
// ---------------------------------------------------------------------------
__global__ __launch_bounds__(256)
void conv_data_k(const float* __restrict__ in, _Float16* __restrict__ hi,
                 _Float16* __restrict__ lo)
{
  const size_t i = ((size_t)blockIdx.x * 256 + threadIdx.x) * 4;
  const float4 v = *reinterpret_cast<const float4*>(in + i);
  f16x4 h, l;
  h.x = (_Float16)v.x; l.x = (_Float16)(v.x - (float)h.x);
  h.y = (_Float16)v.y; l.y = (_Float16)(v.y - (float)h.y);
  h.z = (_Float16)v.z; l.z = (_Float16)(v.z - (float)h.z);
  h.w = (_Float16)v.w; l.w = (_Float16)(v.w - (float)h.w);
  *reinterpret_cast<f16x4*>(hi + i) = h;
  *reinterpret_cast<f16x4*>(lo + i) = l;
}

__global__ __launch_bounds__(256)
void conv_A_k(const float* __restrict__ A, _Float16* __restrict__ Ah,
              _Float16* __restrict__ Al, _Float16* __restrict__ ATh,
              _Float16* __restrict__ ATl)
{
  const int i = blockIdx.x * 256 + threadIdx.x;
  const int r = i >> 9, c = i & 511;
  const float v = A[i];
  const _Float16 h = (_Float16)v;
  const _Float16 l = (_Float16)(v - (float)h);
  Ah[i] = h; Al[i] = l;
  ATh[c * 512 + r] = h; ATl[c * 512 + r] = l;
}

// ---------------------------------------------------------------------------
// Spline prep: pkG[k][j] = {x,y,d,s}; bucketG[k][c] = #{x_j <= -4 + c/32}
// Cell 1/32 = 0.03125 < 2*min-gap 0.0402 -> at most 2 knots per cell.
// ---------------------------------------------------------------------------
__global__ __launch_bounds__(256)
void prep_k(const float* __restrict__ xx, const float* __restrict__ yy,
            const float* __restrict__ dd, float4* __restrict__ pkG,
            unsigned char* __restrict__ bucketG)
{
  __shared__ float xr[MKNOTS], yr[MKNOTS];
  const int k = blockIdx.x, tid = threadIdx.x;
  if (tid < MKNOTS) {
    xr[tid] = xx[k * MKNOTS + tid];
    yr[tid] = yy[k * MKNOTS + tid];
  }
  __syncthreads();
  if (tid < MKNOTS) {
    const float x0 = xr[tid], y0 = yr[tid], d0 = dd[k * MKNOTS + tid];
    float s = 0.f;
    if (tid < MKNOTS - 1) s = (yr[tid + 1] - y0) / (xr[tid + 1] - x0);
    pkG[k * MKNOTS + tid] = float4{x0, y0, d0, s};
  }
  for (int c = tid; c < NCELL; c += 256) {
    const float cl = -4.f + (float)c * 0.03125f;
    int lo = 0, hi = MKNOTS;
    while (lo < hi) { const int mid = (lo + hi) >> 1; if (xr[mid] <= cl) lo = mid + 1; else hi = mid; }
    bucketG[k * NCELL + c] = (unsigned char)lo;
  }
}

// ---------------------------------------------------------------------------
// RQ spline v4: global I/O in R2's proven-coalesced shapes (full-line tile
// loads, 32B-contiguous zH stores); compute thread-per-row from LDS tile with
// register logd accumulation. Knots in LDS SoA (x,y f32; d f16); bucket from
// global (L2-resident, <=2-knot refine). No atomics: partials -> ppart.
// LDS: sX/sY 12.9K each + sD 6.4K + xT 17.4K = 49.6 KB -> 3 blocks/CU.
// ---------------------------------------------------------------------------
__global__ __launch_bounds__(256)
void spline_k(const float* __restrict__ data0, const float4* __restrict__ pkG,
              const unsigned char* __restrict__ bucketG,
              _Float16* __restrict__ zH, float* __restrict__ ppart)
{
  __shared__ float sX[KT * 201];        // 200 knots + 1 pad per row
  __shared__ float sY[KT * 201];
  __shared__ _Float16 sD[KT * 201 + 2];
  __shared__ float xT[TILE * 17];       // 16 x's + pad per row; z overwrites words 0..7

  const int kBase = blockIdx.x * KT;
  const int nBase = blockIdx.y * (TILE * TPB);
  const int tid = threadIdx.x;

  for (int i = tid; i < KT * MKNOTS; i += 256) {
    const int r = i / MKNOTS, c = i - r * MKNOTS;
    const float4 v = pkG[(kBase + r) * MKNOTS + c];
    sX[r * 201 + c] = v.x;
    sY[r * 201 + c] = v.y;
    sD[r * 201 + c] = (_Float16)v.z;
  }
  __syncthreads();

  for (int tile = 0; tile < TPB; ++tile) {
    const int n0 = nBase + tile * TILE;

    // stage x tile: full-line coalesced (4 lanes x float4 per row)
    #pragma unroll
    for (int rr = 0; rr < 4; ++rr) {
      const int r = rr * 64 + (tid >> 2);
      const float4 v = *((const float4*)(data0 + (size_t)(n0 + r) * DIM + kBase) + (tid & 3));
      float* dst = &xT[r * 17 + (tid & 3) * 4];
      dst[0] = v.x; dst[1] = v.y; dst[2] = v.z; dst[3] = v.w;
    }
    __syncthreads();

    // compute: thread -> row n0+tid, 16 independent evals, register logd
    float acc = 0.f;
    float zprev = 0.f;
    #pragma unroll 4
    for (int j = 0; j < KT; ++j) {
      const float x = xT[tid * 17 + j];

      int c = (int)((x + 4.f) * 32.f);
      c = min(max(c, 0), NCELL - 1);
      const int cnt0 = (int)bucketG[(kBase + j) * NCELL + c];   // >= 1 always

      const int p = min(cnt0, MKNOTS - 2);   // <= 198
      const int q0 = p - 1;                  // >= 0
      const float* rx = &sX[j * 201];
      const float xm = rx[q0], x0 = rx[q0 + 1], x1 = rx[q0 + 2], x2 = rx[q0 + 3];
      const int t2 = (x0 < x ? 1 : 0) + (x1 < x ? 1 : 0);
      const int idx = p + t2;                // == #{x_j < x} (see derivation)
      const bool below = (x <= -4.f);
      const bool above = (idx >= MKNOTS);
      const int b = idx - 1;                 // 0..199

      const float xk  = (t2 == 0) ? xm : ((t2 == 1) ? x0 : x1);
      const float xk1 = (t2 == 0) ? x0 : ((t2 == 1) ? x1 : x2);
      const float yk  = sY[j * 201 + b];
      const float yk1 = sY[j * 201 + b + 1];
      const float dk  = (float)sD[j * 201 + b];
      const float dk1 = (float)sD[j * 201 + b + 1];

      const float dxk = xk1 - xk;
      const float rdx = __builtin_amdgcn_rcpf(dxk);
      const float s   = (yk1 - yk) * rdx;
      float xi = (x - xk) * rdx;
      xi = fminf(fmaxf(xi, 0.f), 1.f);
      const float xi1 = 1.f - xi;
      const float g = xi * xi1;
      const float den = s + (dk1 + dk - 2.f * s) * g;
      const float rden = __builtin_amdgcn_rcpf(den);
      const float y_in = yk + s * dxk * (s * xi * xi + dk * g) * rden;
      const float dnum = dk1 * xi * xi + 2.f * s * g + dk * xi1 * xi1;
      const float ld_in = __logf(s * s * dnum * rden * rden);

      const bool edge = below || above;      // both use knot b: linear extension
      const float y  = edge ? (yk + dk * (x - xk)) : y_in;
      const float ld = edge ? __logf(dk) : ld_in;
      acc += ld;

      const float z = y - x;
      if (j & 1) {
        union { _Float16 h[2]; unsigned int u; } pk2;
        pk2.h[0] = (_Float16)zprev; pk2.h[1] = (_Float16)z;
        ((unsigned int*)xT)[tid * 17 + (j >> 1)] = pk2.u;   // in-place, word (j>>1) < j safe
      } else {
        zprev = z;
      }
    }
    ppart[(size_t)blockIdx.x * N_ROWS + n0 + tid] = acc;
    __syncthreads();

    // coop z store: 8 lanes x 4B cover a row's 32B contiguous (R2 shape)
    const int w = tid & 7;
    #pragma unroll
    for (int ri = 0; ri < 8; ++ri) {
      const int r = ri * 32 + (tid >> 3);
      const unsigned int zz = ((const unsigned int*)xT)[r * 17 + w];
      *(unsigned int*)(zH + (size_t)(n0 + r) * DIM + kBase + w * 2) = zz;
    }
    __syncthreads();
  }
}

// logj[n] = sum over 32 k-tiles of ppart[kt][n]
__global__ __launch_bounds__(256)
void reduce_k(const float* __restrict__ ppart, float* __restrict__ logj)
{
  const int n = blockIdx.x * 256 + threadIdx.x;
  float a = 0.f;
  #pragma unroll
  for (int t = 0; t < 32; ++t) a += ppart[(size_t)t * N_ROWS + n];
  logj[n] = a;
}

// ---------------------------------------------------------------------------
extern "C" void kernel_launch(void* const* d_in, const int* in_sizes, int n_in,
                              void* d_out, int out_size, void* d_ws, size_t ws_size,
                              hipStream_t stream)
{
  const float* data  = (const float*)d_in[0];
  const float* A     = (const float*)d_in[1];
  const float* xx    = (const float*)d_in[2];
  const float* yy    = (const float*)d_in[3];
  const float* delta = (const float*)d_in[4];

  float* out  = (float*)d_out;                       // N_ROWS * DIM
  float* logj = out + (size_t)N_ROWS * DIM;          // N_ROWS

  // workspace layout (~258 MiB)
  _Float16* dHi = (_Float16*)d_ws;                   // 64 MiB
  _Float16* dLo = dHi + (size_t)N_ROWS * DIM;        // 64 MiB
  _Float16* Ah  = dLo + (size_t)N_ROWS * DIM;        // 512 KiB each
  _Float16* Al  = Ah + 512 * 512;
  _Float16* ATh = Al + 512 * 512;
  _Float16* ATl = ATh + 512 * 512;
  float* data0  = (float*)(ATl + 512 * 512);         // 128 MiB
  _Float16* zH  = dHi;                               // alias: dHi dead after GEMM1
  // spline tables + partials alias dLo (dead after GEMM1): 1.6M + 192K + 8M
  float4* pkG = (float4*)dLo;
  unsigned char* bucketG = (unsigned char*)(pkG + 512 * MKNOTS);
  float* ppart = (float*)(bucketG + 512 * NCELL);

  conv_A_k<<<1024, 256, 0, stream>>>(A, Ah, Al, ATh, ATl);
  conv_data_k<<<(N_ROWS * DIM) / (256 * 4), 256, 0, stream>>>(data, dHi, dLo);

  // data0 = data @ A  (split-3 f16, fp32-quality)
  gemm_k<true, false><<<dim3(N_ROWS / 128, DIM / 128), 256, 0, stream>>>(
      dHi, dLo, ATh, ATl, nullptr, data0);

  prep_k<<<512, 256, 0, stream>>>(xx, yy, delta, pkG, bucketG);

  spline_k<<<dim3(DIM / KT, N_ROWS / (TILE * TPB)), 256, 0, stream>>>(
      data0, pkG, bucketG, zH, ppart);

  reduce_k<<<N_ROWS / 256, 256, 0, stream>>>(ppart, logj);

  // out = data + z @ A^T  (plain f16)
  gemm_k<false, true><<<dim3(N_ROWS / 128, DIM / 128), 256, 0, stream>>>(
      zH, nullptr, Ah, nullptr, data, out);
}